// Round 1
// baseline (139.209 us; speedup 1.0000x reference)
//
#include <hip/hip_runtime.h>
#include <math.h>

static constexpr int NN   = 4096;
static constexpr int INC  = 256;
static constexpr int OUTC = 64;
#define LRELU_ALPHA 0.2f

__device__ __forceinline__ float lrelu(float x) {
    return fmaxf(x, 0.f) + LRELU_ALPHA * fminf(x, 0.f);
}
__device__ __forceinline__ float elu1(float x) {
    return x > 0.f ? x : (__expf(x) - 1.f);
}

// K1: Wh = H@W (4096x64); f1 = Wh@a1; f2 = Wh@a2. 16 rows/block, 256 blocks.
__global__ __launch_bounds__(256) void k_wh(const float* __restrict__ H,
                                            const float* __restrict__ W,
                                            const float* __restrict__ a,
                                            float* __restrict__ Wh,
                                            float* __restrict__ f1,
                                            float* __restrict__ f2) {
    __shared__ __align__(16) float Wl[INC * OUTC];   // 64 KB
    __shared__ __align__(16) float Hl[16 * INC];     // 16 KB
    const int t = threadIdx.x;
    const int i0 = blockIdx.x * 16;
    {
        const float4* W4 = (const float4*)W;
        float4* Wl4 = (float4*)Wl;
        #pragma unroll
        for (int u = 0; u < 16; ++u) Wl4[u * 256 + t] = W4[u * 256 + t];
        const float4* H4 = (const float4*)(H + i0 * INC);
        float4* Hl4 = (float4*)Hl;
        #pragma unroll
        for (int u = 0; u < 4; ++u) Hl4[u * 256 + t] = H4[u * 256 + t];
    }
    __syncthreads();
    const int c = t & 63;       // channel (lane)
    const int g = t >> 6;       // wave -> row group
    const float a1c = a[c];
    const float a2c = a[OUTC + c];
    float acc[4] = {0.f, 0.f, 0.f, 0.f};
    const float4* Hl4 = (const float4*)Hl;
    for (int k4 = 0; k4 < INC / 4; ++k4) {
        const float w0 = Wl[(k4 * 4 + 0) * OUTC + c];
        const float w1 = Wl[(k4 * 4 + 1) * OUTC + c];
        const float w2 = Wl[(k4 * 4 + 2) * OUTC + c];
        const float w3 = Wl[(k4 * 4 + 3) * OUTC + c];
        #pragma unroll
        for (int s = 0; s < 4; ++s) {
            const float4 h = Hl4[(g + 4 * s) * (INC / 4) + k4];
            acc[s] = fmaf(h.x, w0, fmaf(h.y, w1, fmaf(h.z, w2, fmaf(h.w, w3, acc[s]))));
        }
    }
    #pragma unroll
    for (int s = 0; s < 4; ++s) {
        const int r = g + 4 * s;
        Wh[(i0 + r) * OUTC + c] = acc[s];
        float v1 = acc[s] * a1c;
        float v2 = acc[s] * a2c;
        #pragma unroll
        for (int off = 32; off; off >>= 1) {
            v1 += __shfl_xor(v1, off);
            v2 += __shfl_xor(v2, off);
        }
        if (c == 0) { f1[i0 + r] = v1; f2[i0 + r] = v2; }
    }
}

// K2: mx = max(f2) (single block)
__global__ __launch_bounds__(256) void k_max(const float* __restrict__ f2,
                                             float* __restrict__ mx) {
    __shared__ float red[4];
    const int t = threadIdx.x;
    float m = -3.4e38f;
    for (int idx = t; idx < NN; idx += 256) m = fmaxf(m, f2[idx]);
    #pragma unroll
    for (int off = 32; off; off >>= 1) m = fmaxf(m, __shfl_xor(m, off));
    if ((t & 63) == 0) red[t >> 6] = m;
    __syncthreads();
    if (t == 0) mx[0] = fmaxf(fmaxf(red[0], red[1]), fmaxf(red[2], red[3]));
}

// K3: per (row-tile, j-split): numP[js][i][c] = sum_j mask*p*Wh[j][c],
//     denP[js][i] = sum_j p (unmasked).  64 rows x 512 j per block.
__global__ __launch_bounds__(256) void k_att(const int* __restrict__ adj,
                                             const float* __restrict__ Wh,
                                             const float* __restrict__ f1,
                                             const float* __restrict__ f2,
                                             const float* __restrict__ mx,
                                             float* __restrict__ numP,
                                             float* __restrict__ denP) {
    __shared__ __align__(16) float pm[64 * 68];   // padded stride 68 -> no 4-way bank conflict
    __shared__ __align__(16) float wh[64 * 64];
    const int t = threadIdx.x;
    const int rt = blockIdx.x >> 3;   // row tile 0..63
    const int js = blockIdx.x & 7;    // j split  0..7
    const int i0 = rt * 64;
    const int j0b = js * 512;
    const int q    = t & 15;          // phase A: jj quad; phase B: channel quad
    const int rowg = t >> 4;          // row group 0..15 (both phases)
    const float maxf2 = mx[0];
    float f1r[4], mrow[4];
    #pragma unroll
    for (int s = 0; s < 4; ++s) {
        const float v = f1[i0 + rowg + 16 * s];
        f1r[s] = v;
        mrow[s] = lrelu(v + maxf2);   // exact per-row softmax max (leaky is monotone)
    }
    float dacc[4] = {0.f, 0.f, 0.f, 0.f};
    float4 acc[4];
    #pragma unroll
    for (int s = 0; s < 4; ++s) acc[s] = make_float4(0.f, 0.f, 0.f, 0.f);

    const float4* Wh4 = (const float4*)Wh;
    float4* wh4 = (float4*)wh;
    const float4* pm4 = (const float4*)pm;
    const int4* adj4 = (const int4*)adj;
    const float4* f24 = (const float4*)f2;

    for (int tile = 0; tile < 8; ++tile) {
        const int j0 = j0b + tile * 64;
        // stage Wh tile (coalesced)
        #pragma unroll
        for (int u = 0; u < 4; ++u) {
            const int idx = u * 256 + t;
            wh4[idx] = Wh4[j0 * 16 + idx];
        }
        // phase A: p values + mask -> pm, unmasked sum -> dacc
        const float4 f2v = f24[(j0 >> 2) + q];
        #pragma unroll
        for (int s = 0; s < 4; ++s) {
            const int r = rowg + 16 * s;
            const int4 av = adj4[(((i0 + r) * NN + j0) >> 2) + q];
            const float p0 = __expf(lrelu(f1r[s] + f2v.x) - mrow[s]);
            const float p1 = __expf(lrelu(f1r[s] + f2v.y) - mrow[s]);
            const float p2 = __expf(lrelu(f1r[s] + f2v.z) - mrow[s]);
            const float p3 = __expf(lrelu(f1r[s] + f2v.w) - mrow[s]);
            dacc[s] += (p0 + p1 + p2 + p3);
            float4 st;
            st.x = av.x > 0 ? p0 : 0.f;
            st.y = av.y > 0 ? p1 : 0.f;
            st.z = av.z > 0 ? p2 : 0.f;
            st.w = av.w > 0 ? p3 : 0.f;
            *(float4*)&pm[r * 68 + 4 * q] = st;
        }
        __syncthreads();
        // phase B: acc[r][c] += pm[r][jj] * wh[jj][c]
        for (int qq = 0; qq < 16; ++qq) {
            const float4 w0 = wh4[(qq * 4 + 0) * 16 + q];
            const float4 w1 = wh4[(qq * 4 + 1) * 16 + q];
            const float4 w2 = wh4[(qq * 4 + 2) * 16 + q];
            const float4 w3 = wh4[(qq * 4 + 3) * 16 + q];
            #pragma unroll
            for (int s = 0; s < 4; ++s) {
                const float4 p4 = pm4[(rowg + 16 * s) * 17 + qq];
                acc[s].x = fmaf(p4.x, w0.x, fmaf(p4.y, w1.x, fmaf(p4.z, w2.x, fmaf(p4.w, w3.x, acc[s].x))));
                acc[s].y = fmaf(p4.x, w0.y, fmaf(p4.y, w1.y, fmaf(p4.z, w2.y, fmaf(p4.w, w3.y, acc[s].y))));
                acc[s].z = fmaf(p4.x, w0.z, fmaf(p4.y, w1.z, fmaf(p4.z, w2.z, fmaf(p4.w, w3.z, acc[s].z))));
                acc[s].w = fmaf(p4.x, w0.w, fmaf(p4.y, w1.w, fmaf(p4.z, w2.w, fmaf(p4.w, w3.w, acc[s].w))));
            }
        }
        __syncthreads();
    }
    float4* numP4 = (float4*)numP;
    #pragma unroll
    for (int s = 0; s < 4; ++s) {
        const int r = rowg + 16 * s;
        numP4[(js * NN + i0 + r) * 16 + q] = acc[s];
        float v = dacc[s];
        v += __shfl_xor(v, 1);
        v += __shfl_xor(v, 2);
        v += __shfl_xor(v, 4);
        v += __shfl_xor(v, 8);
        if (q == 0) denP[js * NN + i0 + r] = v;
    }
}

// K4: combine 8 partials, divide, elu
__global__ __launch_bounds__(256) void k_fin(const float* __restrict__ numP,
                                             const float* __restrict__ denP,
                                             float* __restrict__ out) {
    const int id = blockIdx.x * 256 + threadIdx.x;  // one float4 of out
    const int i = id >> 4;
    const int c4 = id & 15;
    const float4* n4 = (const float4*)numP;
    float4 s = make_float4(0.f, 0.f, 0.f, 0.f);
    float den = 0.f;
    #pragma unroll
    for (int p = 0; p < 8; ++p) {
        const float4 v = n4[(p * NN + i) * 16 + c4];
        s.x += v.x; s.y += v.y; s.z += v.z; s.w += v.w;
        den += denP[p * NN + i];
    }
    const float inv = 1.f / den;
    float4 o;
    o.x = elu1(s.x * inv);
    o.y = elu1(s.y * inv);
    o.z = elu1(s.z * inv);
    o.w = elu1(s.w * inv);
    ((float4*)out)[id] = o;
}

extern "C" void kernel_launch(void* const* d_in, const int* in_sizes, int n_in,
                              void* d_out, int out_size, void* d_ws, size_t ws_size,
                              hipStream_t stream) {
    const float* H  = (const float*)d_in[0];
    const int* adj  = (const int*)d_in[1];
    const float* W  = (const float*)d_in[2];
    const float* a  = (const float*)d_in[3];
    float* out = (float*)d_out;
    char* ws = (char*)d_ws;
    // ws layout: Wh 1MB | f1 16KB | f2 16KB | mx | denP 128KB | numP 8MB  (~9.3MB total)
    float* Wh   = (float*)(ws);
    float* f1   = (float*)(ws + (1 << 20));
    float* f2   = (float*)(ws + (1 << 20) + (16 << 10));
    float* mx   = (float*)(ws + (1 << 20) + (32 << 10));
    float* denP = (float*)(ws + (1 << 20) + (64 << 10));
    float* numP = (float*)(ws + (1 << 20) + (256 << 10));
    hipLaunchKernelGGL(k_wh,  dim3(256), dim3(256), 0, stream, H, W, a, Wh, f1, f2);
    hipLaunchKernelGGL(k_max, dim3(1),   dim3(256), 0, stream, f2, mx);
    hipLaunchKernelGGL(k_att, dim3(512), dim3(256), 0, stream, adj, Wh, f1, f2, mx, numP, denP);
    hipLaunchKernelGGL(k_fin, dim3(256), dim3(256), 0, stream, numP, denP, out);
}

// Round 2
// 129.861 us; speedup vs baseline: 1.0720x; 1.0720x over previous
//
#include <hip/hip_runtime.h>
#include <math.h>

static constexpr int NN   = 4096;
static constexpr int INC  = 256;
static constexpr int OUTC = 64;

typedef _Float16 half8 __attribute__((ext_vector_type(8)));
typedef float floatx4 __attribute__((ext_vector_type(4)));

__device__ __forceinline__ float lrelu(float x) {
    return fmaxf(x, 0.f) + 0.2f * fminf(x, 0.f);
}
__device__ __forceinline__ float elu1(float x) {
    return x > 0.f ? x : (__expf(x) - 1.f);
}

// K1: Wh = H@W; store WhT as fp16 transposed (64 x 4096); f1 = Wh@a1; f2 = Wh@a2.
// 16 rows/block, 256 blocks.
__global__ __launch_bounds__(256) void k_wh(const float* __restrict__ H,
                                            const float* __restrict__ W,
                                            const float* __restrict__ a,
                                            unsigned short* __restrict__ WhT,
                                            float* __restrict__ f1,
                                            float* __restrict__ f2) {
    __shared__ __align__(16) float Wl[INC * OUTC];   // 64 KB
    __shared__ __align__(16) float Hl[16 * INC];     // 16 KB
    __shared__ _Float16 Tl[16 * 68];                 // transpose buffer (pad 68)
    const int t = threadIdx.x;
    const int i0 = blockIdx.x * 16;
    {
        const float4* W4 = (const float4*)W;
        float4* Wl4 = (float4*)Wl;
        #pragma unroll
        for (int u = 0; u < 16; ++u) Wl4[u * 256 + t] = W4[u * 256 + t];
        const float4* H4 = (const float4*)(H + i0 * INC);
        float4* Hl4 = (float4*)Hl;
        #pragma unroll
        for (int u = 0; u < 4; ++u) Hl4[u * 256 + t] = H4[u * 256 + t];
    }
    __syncthreads();
    const int c = t & 63;       // channel (lane)
    const int g = t >> 6;       // wave -> row group
    const float a1c = a[c];
    const float a2c = a[OUTC + c];
    float acc[4] = {0.f, 0.f, 0.f, 0.f};
    const float4* Hl4 = (const float4*)Hl;
    for (int k4 = 0; k4 < INC / 4; ++k4) {
        const float w0 = Wl[(k4 * 4 + 0) * OUTC + c];
        const float w1 = Wl[(k4 * 4 + 1) * OUTC + c];
        const float w2 = Wl[(k4 * 4 + 2) * OUTC + c];
        const float w3 = Wl[(k4 * 4 + 3) * OUTC + c];
        #pragma unroll
        for (int s = 0; s < 4; ++s) {
            const float4 h = Hl4[(g + 4 * s) * (INC / 4) + k4];
            acc[s] = fmaf(h.x, w0, fmaf(h.y, w1, fmaf(h.z, w2, fmaf(h.w, w3, acc[s]))));
        }
    }
    #pragma unroll
    for (int s = 0; s < 4; ++s) {
        const int r = g + 4 * s;
        Tl[r * 68 + c] = (_Float16)acc[s];
        float v1 = acc[s] * a1c;
        float v2 = acc[s] * a2c;
        #pragma unroll
        for (int off = 32; off; off >>= 1) {
            v1 += __shfl_xor(v1, off);
            v2 += __shfl_xor(v2, off);
        }
        if (c == 0) { f1[i0 + r] = v1; f2[i0 + r] = v2; }
    }
    __syncthreads();
    // transposed store: WhT[c2][i0 + rs .. rs+3], 8 B per thread
    const int c2 = t >> 2;
    const int rs = (t & 3) * 4;
    ushort4 u;
    u.x = *(const unsigned short*)&Tl[(rs + 0) * 68 + c2];
    u.y = *(const unsigned short*)&Tl[(rs + 1) * 68 + c2];
    u.z = *(const unsigned short*)&Tl[(rs + 2) * 68 + c2];
    u.w = *(const unsigned short*)&Tl[(rs + 3) * 68 + c2];
    *(ushort4*)(WhT + c2 * NN + i0 + rs) = u;
}

// K2: mx = max(f2) (single block)
__global__ __launch_bounds__(256) void k_max(const float* __restrict__ f2,
                                             float* __restrict__ mx) {
    __shared__ float red[4];
    const int t = threadIdx.x;
    float m = -3.4e38f;
    const float4* f24 = (const float4*)f2;
    for (int idx = t; idx < NN / 4; idx += 256) {
        const float4 v = f24[idx];
        m = fmaxf(m, fmaxf(fmaxf(v.x, v.y), fmaxf(v.z, v.w)));
    }
    #pragma unroll
    for (int off = 32; off; off >>= 1) m = fmaxf(m, __shfl_xor(m, off));
    if ((t & 63) == 0) red[t >> 6] = m;
    __syncthreads();
    if (t == 0) mx[0] = fmaxf(fmaxf(red[0], red[1]), fmaxf(red[2], red[3]));
}

// K3: MFMA attention-weighted accumulate.
// grid = 256 row-blocks x 2 j-splits; block = 512 threads = 8 waves.
// Each wave owns disjoint 32-j slices; A-fragment (p, fp16) built in registers
// in exact MFMA A layout (row = lane&15, k = quad*8+i). B from global WhT
// (fp16, L2-resident). No barriers in the K loop.
__global__ __launch_bounds__(512, 4) void k_att(const int* __restrict__ adj,
                                                const _Float16* __restrict__ WhT,
                                                const float* __restrict__ f1,
                                                const float* __restrict__ f2,
                                                const float* __restrict__ mx,
                                                float* __restrict__ numP,
                                                float* __restrict__ denP) {
    __shared__ float sacc[8 * 1024];   // 32 KB: per-wave 16x64 fp32 tiles
    __shared__ float sden[8 * 16];
    const int t = threadIdx.x;
    const int w = t >> 6;          // wave 0..7
    const int l = t & 63;
    const int m = l & 15;          // A row / B col (within 16-tile)
    const int quad = l >> 4;       // k-group
    const int rb = blockIdx.x >> 1;
    const int js = blockIdx.x & 1;
    const int i0 = rb * 16;
    const float maxf2 = mx[0];
    const float f1r = f1[i0 + m];
    const float mrow = lrelu(f1r + maxf2);  // exact row max (lrelu monotone)
    float den = 0.f;
    floatx4 acc[4] = {{0.f,0.f,0.f,0.f},{0.f,0.f,0.f,0.f},{0.f,0.f,0.f,0.f},{0.f,0.f,0.f,0.f}};
    const int jbase = js * 2048 + w * 32 + quad * 8;
    const int* adjrow = adj + (size_t)(i0 + m) * NN;

    for (int it = 0; it < 8; ++it) {
        const int j = jbase + it * 256;
        const int4 a0 = *(const int4*)(adjrow + j);
        const int4 a1 = *(const int4*)(adjrow + j + 4);
        const float4 g0 = *(const float4*)(f2 + j);
        const float4 g1 = *(const float4*)(f2 + j + 4);
        half8 af;
        {
            float p;
            p = __expf(lrelu(f1r + g0.x) - mrow); den += p; af[0] = (a0.x > 0) ? (_Float16)p : (_Float16)0.f;
            p = __expf(lrelu(f1r + g0.y) - mrow); den += p; af[1] = (a0.y > 0) ? (_Float16)p : (_Float16)0.f;
            p = __expf(lrelu(f1r + g0.z) - mrow); den += p; af[2] = (a0.z > 0) ? (_Float16)p : (_Float16)0.f;
            p = __expf(lrelu(f1r + g0.w) - mrow); den += p; af[3] = (a0.w > 0) ? (_Float16)p : (_Float16)0.f;
            p = __expf(lrelu(f1r + g1.x) - mrow); den += p; af[4] = (a1.x > 0) ? (_Float16)p : (_Float16)0.f;
            p = __expf(lrelu(f1r + g1.y) - mrow); den += p; af[5] = (a1.y > 0) ? (_Float16)p : (_Float16)0.f;
            p = __expf(lrelu(f1r + g1.z) - mrow); den += p; af[6] = (a1.z > 0) ? (_Float16)p : (_Float16)0.f;
            p = __expf(lrelu(f1r + g1.w) - mrow); den += p; af[7] = (a1.w > 0) ? (_Float16)p : (_Float16)0.f;
        }
        #pragma unroll
        for (int nt = 0; nt < 4; ++nt) {
            const half8 bf = *(const half8*)(WhT + (size_t)(nt * 16 + m) * NN + j);
            acc[nt] = __builtin_amdgcn_mfma_f32_16x16x32_f16(af, bf, acc[nt], 0, 0, 0);
        }
    }
    // den: lanes {m, m+16, m+32, m+48} hold partials for row m
    den += __shfl_xor(den, 16);
    den += __shfl_xor(den, 32);
    if (l < 16) sden[w * 16 + l] = den;
    // D layout: col = lane&15 (= m), row = quad*4 + reg
    #pragma unroll
    for (int nt = 0; nt < 4; ++nt)
        #pragma unroll
        for (int r = 0; r < 4; ++r)
            sacc[w * 1024 + (quad * 4 + r) * 64 + nt * 16 + m] = acc[nt][r];
    __syncthreads();
    // cross-wave reduce -> partial per j-split
    for (int o = t; o < 1024; o += 512) {
        float s = 0.f;
        #pragma unroll
        for (int w2 = 0; w2 < 8; ++w2) s += sacc[w2 * 1024 + o];
        numP[(size_t)js * NN * 64 + i0 * 64 + o] = s;
    }
    if (t < 16) {
        float s = 0.f;
        #pragma unroll
        for (int w2 = 0; w2 < 8; ++w2) s += sden[w2 * 16 + t];
        denP[js * NN + i0 + t] = s;
    }
}

// K4: combine 2 partials, divide, elu
__global__ __launch_bounds__(256) void k_fin(const float* __restrict__ numP,
                                             const float* __restrict__ denP,
                                             float* __restrict__ out) {
    const int id = blockIdx.x * 256 + threadIdx.x;  // one float4 of out
    const int i = id >> 4;
    const float4* n4 = (const float4*)numP;
    const float4 v0 = n4[id];
    const float4 v1 = n4[id + NN * 16];
    const float den = denP[i] + denP[NN + i];
    const float inv = 1.f / den;
    float4 o;
    o.x = elu1((v0.x + v1.x) * inv);
    o.y = elu1((v0.y + v1.y) * inv);
    o.z = elu1((v0.z + v1.z) * inv);
    o.w = elu1((v0.w + v1.w) * inv);
    ((float4*)out)[id] = o;
}

extern "C" void kernel_launch(void* const* d_in, const int* in_sizes, int n_in,
                              void* d_out, int out_size, void* d_ws, size_t ws_size,
                              hipStream_t stream) {
    const float* H  = (const float*)d_in[0];
    const int* adj  = (const int*)d_in[1];
    const float* W  = (const float*)d_in[2];
    const float* a  = (const float*)d_in[3];
    float* out = (float*)d_out;
    char* ws = (char*)d_ws;
    // ws: WhT 512K | f1 16K | f2 16K | mx | denP 32K | numP 2M  (~3 MB)
    unsigned short* WhT = (unsigned short*)(ws);
    float* f1   = (float*)(ws + (512 << 10));
    float* f2   = (float*)(ws + (528 << 10));
    float* mx   = (float*)(ws + (544 << 10));
    float* denP = (float*)(ws + (560 << 10));
    float* numP = (float*)(ws + (1 << 20));
    hipLaunchKernelGGL(k_wh,  dim3(256), dim3(256), 0, stream, H, W, a, WhT, f1, f2);
    hipLaunchKernelGGL(k_max, dim3(1),   dim3(256), 0, stream, f2, mx);
    hipLaunchKernelGGL(k_att, dim3(512), dim3(512), 0, stream, adj, (const _Float16*)WhT, f1, f2, mx, numP, denP);
    hipLaunchKernelGGL(k_fin, dim3(256), dim3(256), 0, stream, numP, denP, out);
}

// Round 3
// 128.478 us; speedup vs baseline: 1.0835x; 1.0108x over previous
//
#include <hip/hip_runtime.h>
#include <math.h>

static constexpr int NN   = 4096;
static constexpr int INC  = 256;
static constexpr int OUTC = 64;

typedef _Float16 half8 __attribute__((ext_vector_type(8)));
typedef float floatx4 __attribute__((ext_vector_type(4)));

__device__ __forceinline__ float lrelu(float x) {
    return fmaxf(x, 0.f) + 0.2f * fminf(x, 0.f);
}
__device__ __forceinline__ float elu1(float x) {
    return x > 0.f ? x : (__expf(x) - 1.f);
}

// K1: Wh = H@W; store WhT as fp16 transposed (64 x 4096); f1 = Wh@a1; f2 = Wh@a2.
// 16 rows/block, 256 blocks.
__global__ __launch_bounds__(256) void k_wh(const float* __restrict__ H,
                                            const float* __restrict__ W,
                                            const float* __restrict__ a,
                                            unsigned short* __restrict__ WhT,
                                            float* __restrict__ f1,
                                            float* __restrict__ f2) {
    __shared__ __align__(16) float Wl[INC * OUTC];   // 64 KB
    __shared__ __align__(16) float Hl[16 * INC];     // 16 KB
    __shared__ _Float16 Tl[16 * 68];                 // transpose buffer (pad 68)
    const int t = threadIdx.x;
    const int i0 = blockIdx.x * 16;
    {
        const float4* W4 = (const float4*)W;
        float4* Wl4 = (float4*)Wl;
        #pragma unroll
        for (int u = 0; u < 16; ++u) Wl4[u * 256 + t] = W4[u * 256 + t];
        const float4* H4 = (const float4*)(H + i0 * INC);
        float4* Hl4 = (float4*)Hl;
        #pragma unroll
        for (int u = 0; u < 4; ++u) Hl4[u * 256 + t] = H4[u * 256 + t];
    }
    __syncthreads();
    const int c = t & 63;       // channel (lane)
    const int g = t >> 6;       // wave -> row group
    const float a1c = a[c];
    const float a2c = a[OUTC + c];
    float acc[4] = {0.f, 0.f, 0.f, 0.f};
    const float4* Hl4 = (const float4*)Hl;
    for (int k4 = 0; k4 < INC / 4; ++k4) {
        const float w0 = Wl[(k4 * 4 + 0) * OUTC + c];
        const float w1 = Wl[(k4 * 4 + 1) * OUTC + c];
        const float w2 = Wl[(k4 * 4 + 2) * OUTC + c];
        const float w3 = Wl[(k4 * 4 + 3) * OUTC + c];
        #pragma unroll
        for (int s = 0; s < 4; ++s) {
            const float4 h = Hl4[(g + 4 * s) * (INC / 4) + k4];
            acc[s] = fmaf(h.x, w0, fmaf(h.y, w1, fmaf(h.z, w2, fmaf(h.w, w3, acc[s]))));
        }
    }
    #pragma unroll
    for (int s = 0; s < 4; ++s) {
        const int r = g + 4 * s;
        Tl[r * 68 + c] = (_Float16)acc[s];
        float v1 = acc[s] * a1c;
        float v2 = acc[s] * a2c;
        #pragma unroll
        for (int off = 32; off; off >>= 1) {
            v1 += __shfl_xor(v1, off);
            v2 += __shfl_xor(v2, off);
        }
        if (c == 0) { f1[i0 + r] = v1; f2[i0 + r] = v2; }
    }
    __syncthreads();
    // transposed store: WhT[c2][i0 + rs .. rs+3], 8 B per thread
    const int c2 = t >> 2;
    const int rs = (t & 3) * 4;
    ushort4 u;
    u.x = *(const unsigned short*)&Tl[(rs + 0) * 68 + c2];
    u.y = *(const unsigned short*)&Tl[(rs + 1) * 68 + c2];
    u.z = *(const unsigned short*)&Tl[(rs + 2) * 68 + c2];
    u.w = *(const unsigned short*)&Tl[(rs + 3) * 68 + c2];
    *(ushort4*)(WhT + c2 * NN + i0 + rs) = u;
}

// K2: fused attention: per block = 16 rows x ALL 4096 j, 16 waves (1024 thr).
// f2 staged to LDS with block-local max(f2) pre-pass (exact row softmax max via
// monotone lrelu). A-fragment (p, fp16) built in registers in MFMA A layout;
// B straight from L2-resident fp16 WhT. No barriers in K-loop. Epilogue:
// cross-wave LDS reduce, divide by unmasked den, elu, store out.
__global__ __launch_bounds__(1024, 4) void k_att(const int* __restrict__ adj,
                                                 const _Float16* __restrict__ WhT,
                                                 const float* __restrict__ f1,
                                                 const float* __restrict__ f2,
                                                 float* __restrict__ out) {
    __shared__ __align__(16) float sf2[NN];        // 16 KB
    __shared__ __align__(16) float sacc[16 * 1024]; // 64 KB
    __shared__ float sden[16 * 16];
    __shared__ float smax[16];
    const int t = threadIdx.x;
    const int w = t >> 6;          // wave 0..15
    const int l = t & 63;
    const int m = l & 15;          // A row (= output row within tile)
    const int quad = l >> 4;       // k-group
    const int i0 = blockIdx.x * 16;

    // pre-pass: f2 -> LDS, block max
    {
        const float4 v = ((const float4*)f2)[t];
        ((float4*)sf2)[t] = v;
        float mloc = fmaxf(fmaxf(v.x, v.y), fmaxf(v.z, v.w));
        #pragma unroll
        for (int off = 32; off; off >>= 1) mloc = fmaxf(mloc, __shfl_xor(mloc, off));
        if (l == 0) smax[w] = mloc;
    }
    __syncthreads();
    float maxf2 = smax[0];
    #pragma unroll
    for (int k = 1; k < 16; ++k) maxf2 = fmaxf(maxf2, smax[k]);

    const float f1r = f1[i0 + m];
    const float mrow = lrelu(f1r + maxf2);  // exact per-row softmax max
    float den = 0.f;
    floatx4 acc[4] = {{0.f,0.f,0.f,0.f},{0.f,0.f,0.f,0.f},{0.f,0.f,0.f,0.f},{0.f,0.f,0.f,0.f}};
    const int jbase = w * 32 + quad * 8;
    const int* adjrow = adj + (size_t)(i0 + m) * NN;

    #pragma unroll 2
    for (int it = 0; it < 8; ++it) {
        const int j = jbase + it * 512;
        const int4 a0 = *(const int4*)(adjrow + j);
        const int4 a1 = *(const int4*)(adjrow + j + 4);
        const float4 g0 = *(const float4*)(sf2 + j);
        const float4 g1 = *(const float4*)(sf2 + j + 4);
        half8 af;
        {
            float p;
            p = __expf(lrelu(f1r + g0.x) - mrow); den += p; af[0] = (a0.x > 0) ? (_Float16)p : (_Float16)0.f;
            p = __expf(lrelu(f1r + g0.y) - mrow); den += p; af[1] = (a0.y > 0) ? (_Float16)p : (_Float16)0.f;
            p = __expf(lrelu(f1r + g0.z) - mrow); den += p; af[2] = (a0.z > 0) ? (_Float16)p : (_Float16)0.f;
            p = __expf(lrelu(f1r + g0.w) - mrow); den += p; af[3] = (a0.w > 0) ? (_Float16)p : (_Float16)0.f;
            p = __expf(lrelu(f1r + g1.x) - mrow); den += p; af[4] = (a1.x > 0) ? (_Float16)p : (_Float16)0.f;
            p = __expf(lrelu(f1r + g1.y) - mrow); den += p; af[5] = (a1.y > 0) ? (_Float16)p : (_Float16)0.f;
            p = __expf(lrelu(f1r + g1.z) - mrow); den += p; af[6] = (a1.z > 0) ? (_Float16)p : (_Float16)0.f;
            p = __expf(lrelu(f1r + g1.w) - mrow); den += p; af[7] = (a1.w > 0) ? (_Float16)p : (_Float16)0.f;
        }
        #pragma unroll
        for (int nt = 0; nt < 4; ++nt) {
            const half8 bf = *(const half8*)(WhT + (size_t)(nt * 16 + m) * NN + j);
            acc[nt] = __builtin_amdgcn_mfma_f32_16x16x32_f16(af, bf, acc[nt], 0, 0, 0);
        }
    }
    // den: lanes {m, m+16, m+32, m+48} hold partials for row m
    den += __shfl_xor(den, 16);
    den += __shfl_xor(den, 32);
    if (l < 16) sden[w * 16 + l] = den;
    // D layout (verified R2): out row = quad*4 + reg, channel = nt*16 + (lane&15)
    #pragma unroll
    for (int nt = 0; nt < 4; ++nt)
        #pragma unroll
        for (int r = 0; r < 4; ++r)
            sacc[w * 1024 + (quad * 4 + r) * 64 + nt * 16 + m] = acc[nt][r];
    __syncthreads();
    // epilogue: thread t owns output (row = t>>6, ch = t&63) of this 16x64 tile
    float s = 0.f;
    #pragma unroll
    for (int w2 = 0; w2 < 16; ++w2) s += sacc[w2 * 1024 + t];
    float dden = 0.f;
    const int row = t >> 6;
    #pragma unroll
    for (int w2 = 0; w2 < 16; ++w2) dden += sden[w2 * 16 + row];
    out[(size_t)i0 * OUTC + t] = elu1(s / dden);
}

extern "C" void kernel_launch(void* const* d_in, const int* in_sizes, int n_in,
                              void* d_out, int out_size, void* d_ws, size_t ws_size,
                              hipStream_t stream) {
    const float* H  = (const float*)d_in[0];
    const int* adj  = (const int*)d_in[1];
    const float* W  = (const float*)d_in[2];
    const float* a  = (const float*)d_in[3];
    float* out = (float*)d_out;
    char* ws = (char*)d_ws;
    // ws: WhT 512K | f1 16K | f2 16K
    unsigned short* WhT = (unsigned short*)(ws);
    float* f1   = (float*)(ws + (512 << 10));
    float* f2   = (float*)(ws + (528 << 10));
    hipLaunchKernelGGL(k_wh,  dim3(256), dim3(256),  0, stream, H, W, a, WhT, f1, f2);
    hipLaunchKernelGGL(k_att, dim3(256), dim3(1024), 0, stream, adj, (const _Float16*)WhT, f1, f2, out);
}